// Round 1
// baseline (323.187 us; speedup 1.0000x reference)
//
#include <hip/hip_runtime.h>

// Problem: N=4096, D=1024, C=1000, T=32
//   h = x @ W^T  (4096 x 2000), mu = h[:, :1000], logvar = h[:, 1000:]
//   sigma = exp(0.5*logvar)
//   eps = jax.random.normal(key(42), (32,4096,1000))  -- threefry2x32, bit-exact
//   prob = mean_t softmax(mu + sigma*eps), out0 = exp(prob), out1 = sigma

typedef __attribute__((ext_vector_type(8))) _Float16 f16x8;
typedef __attribute__((ext_vector_type(4))) float f32x4;
typedef __attribute__((ext_vector_type(2))) float f32x2;

#define NC_TOT  4096000
#define H_HALF  65536000u   // half of T*N*C = 131072000

// ---------------- fp32 -> fp16 (RNE) ----------------
__device__ __forceinline__ unsigned short f2h(float f) {
  _Float16 h = (_Float16)f;
  return __builtin_bit_cast(unsigned short, h);
}

__global__ __launch_bounds__(256) void convert_kernel(
    const float* __restrict__ x, const float* __restrict__ W,
    unsigned short* __restrict__ xh, unsigned short* __restrict__ wh) {
  int qid = blockIdx.x * 256 + threadIdx.x;
  if (qid < 1048576) {                        // x: 4096*1024/4
    float4 v = ((const float4*)x)[qid];
    ((ushort4*)xh)[qid] = make_ushort4(f2h(v.x), f2h(v.y), f2h(v.z), f2h(v.w));
  } else {
    int q = qid - 1048576;                    // padded W quad index, < 524288
    int row = q >> 8;
    ushort4 o;
    if (row < 2000) {
      float4 v = ((const float4*)W)[q];
      o = make_ushort4(f2h(v.x), f2h(v.y), f2h(v.z), f2h(v.w));
    } else {
      o = make_ushort4(0, 0, 0, 0);
    }
    ((ushort4*)wh)[q] = o;
  }
}

// ---------------- fp16 MFMA GEMM: 128x64 tiles, 1024 blocks (4/CU) ----------------
#define BK 32

typedef __attribute__((address_space(3))) unsigned char lds_byte;
typedef __attribute__((address_space(1))) unsigned char glb_byte;

__device__ __forceinline__ void glds16(const unsigned short* g, unsigned short* l) {
  __builtin_amdgcn_global_load_lds((const glb_byte*)g, (lds_byte*)l, 16, 0, 0);
}

__global__ __launch_bounds__(256) void gemm_kernel(
    const unsigned short* __restrict__ Ah,    // [4096][1024] fp16 bits
    const unsigned short* __restrict__ Bh,    // [2048][1024] fp16 bits, padded
    float* __restrict__ mu,                   // [4096][1000]
    float* __restrict__ sigma_out) {          // d_out + NC_TOT
  const int K = 1024;
  __shared__ unsigned short As[128 * BK];     // 8 KB
  __shared__ unsigned short Bs[64 * BK];      // 4 KB

  int id  = blockIdx.x;                 // 0..1023
  int xcd = id & 7;
  int q9  = id >> 3;                    // 0..127
  int by  = xcd * 4 + (q9 >> 5);        // 0..31
  int bx  = q9 & 31;                    // 0..31

  int tid  = threadIdx.x;
  int w    = tid >> 6;
  int lane = tid & 63;
  int wr   = (w >> 1) * 64;             // wave row offset (0/64)
  int wc   = (w & 1) * 32;              // wave col offset (0/32)
  int lrow = lane & 15;
  int kq   = lane >> 4;

  f32x4 acc[4][2];
  for (int i = 0; i < 4; i++)
    for (int j = 0; j < 2; j++) acc[i][j] = (f32x4){0.f, 0.f, 0.f, 0.f};

  int srow = w * 16 + (lane >> 2);
  int scol = (lane & 3) * 8;
  const unsigned short* Ap = Ah + (by * 128 + srow) * K + scol;
  const unsigned short* Bp = Bh + (bx * 64  + srow) * K + scol;   // srow < 64
  unsigned short* lA = As + w * 512;
  unsigned short* lB = Bs + w * 512;

  for (int kk = 0; kk < K; kk += BK) {
    __syncthreads();
    glds16(Ap + kk,          lA);             // A rows 0..63
    glds16(Ap + kk + 64 * K, lA + 2048);      // A rows 64..127
    glds16(Bp + kk,          lB);             // B rows 0..63
    __syncthreads();

    f16x8 a[4], b[2];
    for (int i = 0; i < 4; i++)
      a[i] = *(const f16x8*)(As + (wr + i * 16 + lrow) * BK + kq * 8);
    for (int j = 0; j < 2; j++)
      b[j] = *(const f16x8*)(Bs + (wc + j * 16 + lrow) * BK + kq * 8);
    for (int i = 0; i < 4; i++)
      for (int j = 0; j < 2; j++)
        acc[i][j] = __builtin_amdgcn_mfma_f32_16x16x32_f16(a[i], b[j], acc[i][j], 0, 0, 0);
  }

  // C/D layout: col = lane&15 (N), row = (lane>>4)*4 + reg (M)
  int orow0 = by * 128 + wr + (lane >> 4) * 4;
  int ocol0 = bx * 64 + wc + (lane & 15);
  for (int i = 0; i < 4; i++) {
    for (int j = 0; j < 2; j++) {
      int c = ocol0 + j * 16;
      for (int v = 0; v < 4; v++) {
        int r = orow0 + i * 16 + v;
        float val = acc[i][j][v];
        if (c < 1000)       mu[r * 1000 + c] = val;
        else if (c < 2000)  sigma_out[r * 1000 + (c - 1000)] = __expf(0.5f * val);
      }
    }
  }
}

// ---------------- threefry2x32, key = (0, 42) ----------------
// r9: rotates forced to v_alignbit_b32 (rotl(x,r) == rotr(x,32-r)).
__device__ __forceinline__ unsigned rotl_(unsigned x, unsigned r) {
  return __builtin_amdgcn_alignbit(x, x, 32u - r);
}

__device__ __forceinline__ void threefry(unsigned x0, unsigned x1,
                                         unsigned& o0, unsigned& o1) {
  const unsigned ks1 = 42u;
  const unsigned ks2 = 0x1BD11BDAu ^ 42u;
#define TF_RND(r) { x0 += x1; x1 = rotl_(x1, r); x1 ^= x0; }
  x1 += ks1;
  TF_RND(13) TF_RND(15) TF_RND(26) TF_RND(6)
  x0 += ks1;  x1 += ks2 + 1u;
  TF_RND(17) TF_RND(29) TF_RND(16) TF_RND(24)
  x0 += ks2;  x1 += 2u;
  TF_RND(13) TF_RND(15) TF_RND(26) TF_RND(6)
  x1 += ks1 + 3u;
  TF_RND(17) TF_RND(29) TF_RND(16) TF_RND(24)
  x0 += ks1;  x1 += ks2 + 4u;
  TF_RND(13) TF_RND(15) TF_RND(26) TF_RND(6)
  x0 += ks2;  x1 += 5u;
#undef TF_RND
  o0 = x0; o1 = x1;
}

__device__ __forceinline__ f32x2 splat2(float c) { return (f32x2){c, c}; }

// Tail branch of erfinv; returns p*x WITHOUT the sqrt2 factor
// (sqrt2*log2e is folded into the precomputed sigma scale).
__device__ __forceinline__ float erfinv_big_p(float x, float lg) {
  float w = lg * -0.69314718f;
  float v = __fsqrt_rn(w) - 3.0f;
  float p = -0.000200214257f;
  p = fmaf(p, v, 0.000100950558f);
  p = fmaf(p, v, 0.00134934322f);
  p = fmaf(p, v, -0.00367342844f);
  p = fmaf(p, v, 0.00573950773f);
  p = fmaf(p, v, -0.0076224613f);
  p = fmaf(p, v, 0.00943887047f);
  p = fmaf(p, v, 1.00167406f);
  p = fmaf(p, v, 2.83297682f);
  return p * x;
}

// normal WITHOUT the sqrt2 factor: returns p(v)*x;  v = fma(log2(1-x^2), -ln2, -2.5)
__device__ __forceinline__ f32x2 normal2p(f32x2 x) {
  f32x2 t = __builtin_elementwise_fma(-x, x, splat2(1.0f));
  f32x2 lg;
  lg.x = __builtin_amdgcn_logf(t.x);
  lg.y = __builtin_amdgcn_logf(t.y);
  f32x2 v = __builtin_elementwise_fma(lg, splat2(-0.69314718f), splat2(-2.5f));
  f32x2 p = splat2(2.81022636e-08f);
  p = __builtin_elementwise_fma(p, v, splat2(3.43273939e-07f));
  p = __builtin_elementwise_fma(p, v, splat2(-3.5233877e-06f));
  p = __builtin_elementwise_fma(p, v, splat2(-4.39150654e-06f));
  p = __builtin_elementwise_fma(p, v, splat2(0.00021858087f));
  p = __builtin_elementwise_fma(p, v, splat2(-0.00125372503f));
  p = __builtin_elementwise_fma(p, v, splat2(-0.00417768164f));
  p = __builtin_elementwise_fma(p, v, splat2(0.246640727f));
  p = __builtin_elementwise_fma(p, v, splat2(1.50140941f));
  f32x2 r = p * x;
  if (lg.x <= -7.2134752f) r.x = erfinv_big_p(x.x, lg.x);   // w >= 5, rare
  if (lg.y <= -7.2134752f) r.y = erfinv_big_p(x.y, lg.y);
  return r;
}

__device__ __forceinline__ f32x2 bits_to_u2(unsigned b0, unsigned b1) {
  f32x2 f;
  f.x = __builtin_bit_cast(float, (b0 >> 9) | 0x3f800000u);
  f.y = __builtin_bit_cast(float, (b1 >> 9) | 0x3f800000u);
  f = f - splat2(1.0f);
  return __builtin_elementwise_fma(f, splat2(2.0f), splat2(-0.99999994f));
}

// ---------------- sampling v2: wave-split classes to kill spills ----------------
// Block = row n. 4 waves: wave (tg = w>>1, half = w&1).
// Wave handles 8 class-chunks (512 classes, half) x 8 t-pairs (t = tg*8+it, pairs (t,t+16)).
// Live set: mu2[8]+sg2[8]+prob[8]+e[8](f32x2) ~ 48 regs -> no spill.
// Cross-wave softmax denominator via double-buffered LDS slot, 1 barrier/it.
__global__ __launch_bounds__(256) void sample_kernel(
    const float* __restrict__ mu,      // ws
    const float* __restrict__ sigma,   // d_out + NC
    float* __restrict__ out0) {        // d_out
  int n    = blockIdx.x;
  int tid  = threadIdx.x;
  int lane = tid & 63;
  int w    = tid >> 6;
  int half = w & 1;                    // class half: chunks half*8 .. half*8+7
  int tg   = w >> 1;                   // t = tg*8 + it, pairs (t, t+16)
  __shared__ float pbuf[2][1024];      // [tg][class]
  __shared__ f32x2 sred[2][2][2];      // [it&1][tg][half]

  int cb    = n * 1000;
  int cbase = half * 512;

  // exp(mu + sigma*sqrt2*erfinvp) == exp2( mu*L2E + (sigma*sqrt2*L2E)*erfinvp )
  const float L2E    = 1.44269504f;
  const float SQ2L2E = 1.41421356f * 1.44269504f;

  float mu2[8], sg2[8], prob[8];
#pragma unroll
  for (int j = 0; j < 8; j++) {
    int c = cbase + j * 64 + lane;
    bool val = (c < 1000);
    mu2[j]  = val ? mu[cb + c] * L2E       : -1e30f;  // exp2(-1e30) == 0: pad classes
    sg2[j]  = val ? sigma[cb + c] * SQ2L2E : 0.f;
    prob[j] = 0.f;
  }

  f32x2 e[8];
#pragma unroll 1
  for (int it = 0; it < 8; it++) {
    int t = tg * 8 + it;                               // 0..15
    unsigned ib = (unsigned)(t * 4096000 + cb + cbase) + (unsigned)lane;
    f32x2 s = splat2(0.f);
#pragma unroll
    for (int j = 0; j < 8; j++) {
      unsigned i0 = ib + (unsigned)(j * 64);
      unsigned o0, o1;
      threefry(i0, i0 + H_HALF, o0, o1);
      f32x2 epsp = normal2p(bits_to_u2(o0, o1));
      f32x2 ev;
      ev.x = __builtin_amdgcn_exp2f(fmaf(sg2[j], epsp.x, mu2[j]));  // sample t
      ev.y = __builtin_amdgcn_exp2f(fmaf(sg2[j], epsp.y, mu2[j]));  // sample t+16
      e[j] = ev;
      s = s + ev;
    }
#pragma unroll
    for (int m = 1; m < 64; m <<= 1) {
      s.x += __shfl_xor(s.x, m, 64);
      s.y += __shfl_xor(s.y, m, 64);
    }
    if (lane == 0) sred[it & 1][tg][half] = s;
    __syncthreads();   // double-buffered on it&1: one barrier per it is race-free
    f32x2 s0 = sred[it & 1][tg][0];
    f32x2 s1 = sred[it & 1][tg][1];
    float rA = __builtin_amdgcn_rcpf(s0.x + s1.x);
    float rB = __builtin_amdgcn_rcpf(s0.y + s1.y);
#pragma unroll
    for (int j = 0; j < 8; j++)
      prob[j] = fmaf(e[j].x, rA, fmaf(e[j].y, rB, prob[j]));
  }

#pragma unroll
  for (int j = 0; j < 8; j++)
    pbuf[tg][cbase + j * 64 + lane] = prob[j];
  __syncthreads();
#pragma unroll
  for (int k = 0; k < 4; k++) {
    int c = tid + k * 256;
    if (c < 1000) {
      float sm = pbuf[0][c] + pbuf[1][c];
      out0[cb + c] = __builtin_amdgcn_exp2f(sm * (0.03125f * 1.44269504f));
    }
  }
}

// ---------------- launch ----------------
extern "C" void kernel_launch(void* const* d_in, const int* in_sizes, int n_in,
                              void* d_out, int out_size, void* d_ws, size_t ws_size,
                              hipStream_t stream) {
  const float* x = (const float*)d_in[0];   // 4096*1024
  const float* W = (const float*)d_in[1];   // 2000*1024
  float* out = (float*)d_out;               // [mu_out | sigma], each 4096000

  unsigned short* xh = (unsigned short*)d_ws;                        //  8,388,608 B
  unsigned short* wh = (unsigned short*)((char*)d_ws + 8388608);     //  4,194,304 B
  float*          mu = (float*)((char*)d_ws + 12582912);             // 16,384,000 B
  float* sigma = out + NC_TOT;

  convert_kernel<<<6144, 256, 0, stream>>>(x, W, xh, wh);
  gemm_kernel<<<1024, 256, 0, stream>>>(xh, wh, mu, sigma);
  sample_kernel<<<4096, 256, 0, stream>>>(mu, sigma, out);
}

// Round 2
// 281.455 us; speedup vs baseline: 1.1483x; 1.1483x over previous
//
#include <hip/hip_runtime.h>

// Problem: N=4096, D=1024, C=1000, T=32
//   h = x @ W^T  (4096 x 2000), mu = h[:, :1000], logvar = h[:, 1000:]
//   sigma = exp(0.5*logvar)
//   eps = jax.random.normal(key(42), (32,4096,1000))  -- threefry2x32, bit-exact
//   prob = mean_t softmax(mu + sigma*eps), out0 = exp(prob), out1 = sigma

typedef __attribute__((ext_vector_type(8))) _Float16 f16x8;
typedef __attribute__((ext_vector_type(4))) float f32x4;
typedef __attribute__((ext_vector_type(2))) float f32x2;

#define NC_TOT  4096000
#define H_HALF  65536000u   // half of T*N*C = 131072000

// ---------------- fp32 -> fp16 (RNE) ----------------
__device__ __forceinline__ unsigned short f2h(float f) {
  _Float16 h = (_Float16)f;
  return __builtin_bit_cast(unsigned short, h);
}

__global__ __launch_bounds__(256) void convert_kernel(
    const float* __restrict__ x, const float* __restrict__ W,
    unsigned short* __restrict__ xh, unsigned short* __restrict__ wh) {
  int qid = blockIdx.x * 256 + threadIdx.x;
  if (qid < 1048576) {                        // x: 4096*1024/4
    float4 v = ((const float4*)x)[qid];
    ((ushort4*)xh)[qid] = make_ushort4(f2h(v.x), f2h(v.y), f2h(v.z), f2h(v.w));
  } else {
    int q = qid - 1048576;                    // padded W quad index, < 524288
    int row = q >> 8;
    ushort4 o;
    if (row < 2000) {
      float4 v = ((const float4*)W)[q];
      o = make_ushort4(f2h(v.x), f2h(v.y), f2h(v.z), f2h(v.w));
    } else {
      o = make_ushort4(0, 0, 0, 0);
    }
    ((ushort4*)wh)[q] = o;
  }
}

// ---------------- fp16 MFMA GEMM: 128x64 tiles, 1024 blocks (4/CU) ----------------
#define BK 32

typedef __attribute__((address_space(3))) unsigned char lds_byte;
typedef __attribute__((address_space(1))) unsigned char glb_byte;

__device__ __forceinline__ void glds16(const unsigned short* g, unsigned short* l) {
  __builtin_amdgcn_global_load_lds((const glb_byte*)g, (lds_byte*)l, 16, 0, 0);
}

__global__ __launch_bounds__(256) void gemm_kernel(
    const unsigned short* __restrict__ Ah,    // [4096][1024] fp16 bits
    const unsigned short* __restrict__ Bh,    // [2048][1024] fp16 bits, padded
    float* __restrict__ mu,                   // [4096][1000]
    float* __restrict__ sigma_out) {          // d_out + NC_TOT
  const int K = 1024;
  __shared__ unsigned short As[128 * BK];     // 8 KB
  __shared__ unsigned short Bs[64 * BK];      // 4 KB

  int id  = blockIdx.x;                 // 0..1023
  int xcd = id & 7;
  int q9  = id >> 3;                    // 0..127
  int by  = xcd * 4 + (q9 >> 5);        // 0..31
  int bx  = q9 & 31;                    // 0..31

  int tid  = threadIdx.x;
  int w    = tid >> 6;
  int lane = tid & 63;
  int wr   = (w >> 1) * 64;             // wave row offset (0/64)
  int wc   = (w & 1) * 32;              // wave col offset (0/32)
  int lrow = lane & 15;
  int kq   = lane >> 4;

  f32x4 acc[4][2];
  for (int i = 0; i < 4; i++)
    for (int j = 0; j < 2; j++) acc[i][j] = (f32x4){0.f, 0.f, 0.f, 0.f};

  int srow = w * 16 + (lane >> 2);
  int scol = (lane & 3) * 8;
  const unsigned short* Ap = Ah + (by * 128 + srow) * K + scol;
  const unsigned short* Bp = Bh + (bx * 64  + srow) * K + scol;   // srow < 64
  unsigned short* lA = As + w * 512;
  unsigned short* lB = Bs + w * 512;

  for (int kk = 0; kk < K; kk += BK) {
    __syncthreads();
    glds16(Ap + kk,          lA);             // A rows 0..63
    glds16(Ap + kk + 64 * K, lA + 2048);      // A rows 64..127
    glds16(Bp + kk,          lB);             // B rows 0..63
    __syncthreads();

    f16x8 a[4], b[2];
    for (int i = 0; i < 4; i++)
      a[i] = *(const f16x8*)(As + (wr + i * 16 + lrow) * BK + kq * 8);
    for (int j = 0; j < 2; j++)
      b[j] = *(const f16x8*)(Bs + (wc + j * 16 + lrow) * BK + kq * 8);
    for (int i = 0; i < 4; i++)
      for (int j = 0; j < 2; j++)
        acc[i][j] = __builtin_amdgcn_mfma_f32_16x16x32_f16(a[i], b[j], acc[i][j], 0, 0, 0);
  }

  // C/D layout: col = lane&15 (N), row = (lane>>4)*4 + reg (M)
  int orow0 = by * 128 + wr + (lane >> 4) * 4;
  int ocol0 = bx * 64 + wc + (lane & 15);
  for (int i = 0; i < 4; i++) {
    for (int j = 0; j < 2; j++) {
      int c = ocol0 + j * 16;
      for (int v = 0; v < 4; v++) {
        int r = orow0 + i * 16 + v;
        float val = acc[i][j][v];
        if (c < 1000)       mu[r * 1000 + c] = val;
        else if (c < 2000)  sigma_out[r * 1000 + (c - 1000)] = __expf(0.5f * val);
      }
    }
  }
}

// ---------------- threefry2x32, key = (0, 42) ----------------
// rotl forced to single v_alignbit_b32 (rotl(x,r) == rotr(x,32-r)).
__device__ __forceinline__ unsigned rotl_(unsigned x, unsigned r) {
  return __builtin_amdgcn_alignbit(x, x, 32u - r);
}

__device__ __forceinline__ void threefry(unsigned x0, unsigned x1,
                                         unsigned& o0, unsigned& o1) {
  const unsigned ks1 = 42u;
  const unsigned ks2 = 0x1BD11BDAu ^ 42u;
#define TF_RND(r) { x0 += x1; x1 = rotl_(x1, r); x1 ^= x0; }
  x1 += ks1;
  TF_RND(13) TF_RND(15) TF_RND(26) TF_RND(6)
  x0 += ks1;  x1 += ks2 + 1u;
  TF_RND(17) TF_RND(29) TF_RND(16) TF_RND(24)
  x0 += ks2;  x1 += 2u;
  TF_RND(13) TF_RND(15) TF_RND(26) TF_RND(6)
  x1 += ks1 + 3u;
  TF_RND(17) TF_RND(29) TF_RND(16) TF_RND(24)
  x0 += ks1;  x1 += ks2 + 4u;
  TF_RND(13) TF_RND(15) TF_RND(26) TF_RND(6)
  x0 += ks2;  x1 += 5u;
#undef TF_RND
  o0 = x0; o1 = x1;
}

__device__ __forceinline__ f32x2 splat2(float c) { return (f32x2){c, c}; }

// Tail branch of erfinv; returns p*x WITHOUT the sqrt2 factor
// (sqrt2*log2e is folded into the precomputed sigma scale).
__device__ __forceinline__ float erfinv_big_p(float x, float lg) {
  float w = lg * -0.69314718f;
  float v = __fsqrt_rn(w) - 3.0f;
  float p = -0.000200214257f;
  p = fmaf(p, v, 0.000100950558f);
  p = fmaf(p, v, 0.00134934322f);
  p = fmaf(p, v, -0.00367342844f);
  p = fmaf(p, v, 0.00573950773f);
  p = fmaf(p, v, -0.0076224613f);
  p = fmaf(p, v, 0.00943887047f);
  p = fmaf(p, v, 1.00167406f);
  p = fmaf(p, v, 2.83297682f);
  return p * x;
}

// normal WITHOUT the sqrt2 factor: returns p(v)*x;  v = fma(log2(1-x^2), -ln2, -2.5)
__device__ __forceinline__ f32x2 normal2p(f32x2 x) {
  f32x2 t = __builtin_elementwise_fma(-x, x, splat2(1.0f));
  f32x2 lg;
  lg.x = __builtin_amdgcn_logf(t.x);
  lg.y = __builtin_amdgcn_logf(t.y);
  f32x2 v = __builtin_elementwise_fma(lg, splat2(-0.69314718f), splat2(-2.5f));
  f32x2 p = splat2(2.81022636e-08f);
  p = __builtin_elementwise_fma(p, v, splat2(3.43273939e-07f));
  p = __builtin_elementwise_fma(p, v, splat2(-3.5233877e-06f));
  p = __builtin_elementwise_fma(p, v, splat2(-4.39150654e-06f));
  p = __builtin_elementwise_fma(p, v, splat2(0.00021858087f));
  p = __builtin_elementwise_fma(p, v, splat2(-0.00125372503f));
  p = __builtin_elementwise_fma(p, v, splat2(-0.00417768164f));
  p = __builtin_elementwise_fma(p, v, splat2(0.246640727f));
  p = __builtin_elementwise_fma(p, v, splat2(1.50140941f));
  f32x2 r = p * x;
  if (lg.x <= -7.2134752f) r.x = erfinv_big_p(x.x, lg.x);   // w >= 5, rare
  if (lg.y <= -7.2134752f) r.y = erfinv_big_p(x.y, lg.y);
  return r;
}

__device__ __forceinline__ f32x2 bits_to_u2(unsigned b0, unsigned b1) {
  f32x2 f;
  f.x = __builtin_bit_cast(float, (b0 >> 9) | 0x3f800000u);
  f.y = __builtin_bit_cast(float, (b1 >> 9) | 0x3f800000u);
  f = f - splat2(1.0f);
  return __builtin_elementwise_fma(f, splat2(2.0f), splat2(-0.99999994f));
}

// ---------------- sampling: round-0 structure + exp2 folds + VGPR headroom ----------------
// 1 block per row n; wave w owns t-pairs 4w..4w+3; all 1000 c in 16 reg chunks.
// Per-wave-independent softmax (no mid-loop barriers). e[16] kept in registers.
// __launch_bounds__(256,2): min 2 waves/EU -> VGPR cap 256, live set (~95) fits, no spills.
__global__ __launch_bounds__(256, 2) void sample_kernel(
    const float* __restrict__ mu,      // ws
    const float* __restrict__ sigma,   // d_out + NC
    float* __restrict__ out0) {        // d_out
  int n    = blockIdx.x;
  int tid  = threadIdx.x;
  int lane = tid & 63, w = tid >> 6;
  __shared__ float pbuf[4][1024];

  // exp(mu + sigma*sqrt2*erfinvp) == exp2( mu*L2E + (sigma*sqrt2*L2E)*erfinvp )
  const float L2E    = 1.44269504f;
  const float SQ2L2E = 1.41421356f * 1.44269504f;

  int cb = n * 1000;
  float mu2[16], sg2[16], prob[16];
#pragma unroll
  for (int j = 0; j < 16; j++) {
    int c = j * 64 + lane;
    bool val = (c < 1000);
    mu2[j]  = val ? mu[cb + c] * L2E       : -1e30f;  // exp2(-1e30)==0: pad classes
    sg2[j]  = val ? sigma[cb + c] * SQ2L2E : 0.f;
    prob[j] = 0.f;
  }

  f32x2 e[16];
#pragma unroll 1
  for (int it = 0; it < 4; it++) {
    int t = w * 4 + it;
    unsigned ib = (unsigned)(t * 4096000 + cb) + (unsigned)lane;
    f32x2 s = splat2(0.f);
#pragma unroll
    for (int j = 0; j < 16; j++) {
      unsigned i0 = ib + (unsigned)(j * 64);
      unsigned o0, o1;
      threefry(i0, i0 + H_HALF, o0, o1);
      f32x2 epsp = normal2p(bits_to_u2(o0, o1));
      f32x2 ev;
      ev.x = __builtin_amdgcn_exp2f(fmaf(sg2[j], epsp.x, mu2[j]));  // sample t
      ev.y = __builtin_amdgcn_exp2f(fmaf(sg2[j], epsp.y, mu2[j]));  // sample t+16
      e[j] = ev;
      s = s + ev;
    }
#pragma unroll
    for (int m = 1; m < 64; m <<= 1) {
      s.x += __shfl_xor(s.x, m, 64);
      s.y += __shfl_xor(s.y, m, 64);
    }
    float rA = __builtin_amdgcn_rcpf(s.x);
    float rB = __builtin_amdgcn_rcpf(s.y);
#pragma unroll
    for (int j = 0; j < 16; j++)
      prob[j] = fmaf(e[j].x, rA, fmaf(e[j].y, rB, prob[j]));
  }

#pragma unroll
  for (int j = 0; j < 16; j++)
    pbuf[w][j * 64 + lane] = prob[j];
  __syncthreads();
#pragma unroll
  for (int k = 0; k < 4; k++) {
    int c = tid + k * 256;
    if (c < 1000) {
      float sm = pbuf[0][c] + pbuf[1][c] + pbuf[2][c] + pbuf[3][c];
      out0[cb + c] = __builtin_amdgcn_exp2f(sm * (0.03125f * 1.44269504f));
    }
  }
}

// ---------------- launch ----------------
extern "C" void kernel_launch(void* const* d_in, const int* in_sizes, int n_in,
                              void* d_out, int out_size, void* d_ws, size_t ws_size,
                              hipStream_t stream) {
  const float* x = (const float*)d_in[0];   // 4096*1024
  const float* W = (const float*)d_in[1];   // 2000*1024
  float* out = (float*)d_out;               // [mu_out | sigma], each 4096000

  unsigned short* xh = (unsigned short*)d_ws;                        //  8,388,608 B
  unsigned short* wh = (unsigned short*)((char*)d_ws + 8388608);     //  4,194,304 B
  float*          mu = (float*)((char*)d_ws + 12582912);             // 16,384,000 B
  float* sigma = out + NC_TOT;

  convert_kernel<<<6144, 256, 0, stream>>>(x, W, xh, wh);
  gemm_kernel<<<1024, 256, 0, stream>>>(xh, wh, mu, sigma);
  sample_kernel<<<4096, 256, 0, stream>>>(mu, sigma, out);
}

// Round 3
// 280.714 us; speedup vs baseline: 1.1513x; 1.0026x over previous
//
#include <hip/hip_runtime.h>

// Problem: N=4096, D=1024, C=1000, T=32
//   h = x @ W^T  (4096 x 2000), mu = h[:, :1000], logvar = h[:, 1000:]
//   sigma = exp(0.5*logvar)
//   eps = jax.random.normal(key(42), (32,4096,1000))  -- threefry2x32, bit-exact
//   prob = mean_t softmax(mu + sigma*eps), out0 = exp(prob), out1 = sigma

typedef __attribute__((ext_vector_type(8))) _Float16 f16x8;
typedef __attribute__((ext_vector_type(4))) float f32x4;
typedef __attribute__((ext_vector_type(2))) float f32x2;

#define NC_TOT  4096000
#define H_HALF  65536000u   // half of T*N*C = 131072000

// ---------------- fp32 -> fp16 (RNE) ----------------
__device__ __forceinline__ unsigned short f2h(float f) {
  _Float16 h = (_Float16)f;
  return __builtin_bit_cast(unsigned short, h);
}

__global__ __launch_bounds__(256) void convert_kernel(
    const float* __restrict__ x, const float* __restrict__ W,
    unsigned short* __restrict__ xh, unsigned short* __restrict__ wh) {
  int qid = blockIdx.x * 256 + threadIdx.x;
  if (qid < 1048576) {                        // x: 4096*1024/4
    float4 v = ((const float4*)x)[qid];
    ((ushort4*)xh)[qid] = make_ushort4(f2h(v.x), f2h(v.y), f2h(v.z), f2h(v.w));
  } else {
    int q = qid - 1048576;                    // padded W quad index, < 524288
    int row = q >> 8;
    ushort4 o;
    if (row < 2000) {
      float4 v = ((const float4*)W)[q];
      o = make_ushort4(f2h(v.x), f2h(v.y), f2h(v.z), f2h(v.w));
    } else {
      o = make_ushort4(0, 0, 0, 0);
    }
    ((ushort4*)wh)[q] = o;
  }
}

// ---------------- fp16 MFMA GEMM: 128x64 tiles, 1024 blocks (4/CU) ----------------
#define BK 32

typedef __attribute__((address_space(3))) unsigned char lds_byte;
typedef __attribute__((address_space(1))) unsigned char glb_byte;

__device__ __forceinline__ void glds16(const unsigned short* g, unsigned short* l) {
  __builtin_amdgcn_global_load_lds((const glb_byte*)g, (lds_byte*)l, 16, 0, 0);
}

__global__ __launch_bounds__(256) void gemm_kernel(
    const unsigned short* __restrict__ Ah,    // [4096][1024] fp16 bits
    const unsigned short* __restrict__ Bh,    // [2048][1024] fp16 bits, padded
    float* __restrict__ mu,                   // [4096][1000]
    float* __restrict__ sigma_out) {          // d_out + NC_TOT
  const int K = 1024;
  __shared__ unsigned short As[128 * BK];     // 8 KB
  __shared__ unsigned short Bs[64 * BK];      // 4 KB

  int id  = blockIdx.x;                 // 0..1023
  int xcd = id & 7;
  int q9  = id >> 3;                    // 0..127
  int by  = xcd * 4 + (q9 >> 5);        // 0..31
  int bx  = q9 & 31;                    // 0..31

  int tid  = threadIdx.x;
  int w    = tid >> 6;
  int lane = tid & 63;
  int wr   = (w >> 1) * 64;             // wave row offset (0/64)
  int wc   = (w & 1) * 32;              // wave col offset (0/32)
  int lrow = lane & 15;
  int kq   = lane >> 4;

  f32x4 acc[4][2];
  for (int i = 0; i < 4; i++)
    for (int j = 0; j < 2; j++) acc[i][j] = (f32x4){0.f, 0.f, 0.f, 0.f};

  int srow = w * 16 + (lane >> 2);
  int scol = (lane & 3) * 8;
  const unsigned short* Ap = Ah + (by * 128 + srow) * K + scol;
  const unsigned short* Bp = Bh + (bx * 64  + srow) * K + scol;   // srow < 64
  unsigned short* lA = As + w * 512;
  unsigned short* lB = Bs + w * 512;

  for (int kk = 0; kk < K; kk += BK) {
    __syncthreads();
    glds16(Ap + kk,          lA);             // A rows 0..63
    glds16(Ap + kk + 64 * K, lA + 2048);      // A rows 64..127
    glds16(Bp + kk,          lB);             // B rows 0..63
    __syncthreads();

    f16x8 a[4], b[2];
    for (int i = 0; i < 4; i++)
      a[i] = *(const f16x8*)(As + (wr + i * 16 + lrow) * BK + kq * 8);
    for (int j = 0; j < 2; j++)
      b[j] = *(const f16x8*)(Bs + (wc + j * 16 + lrow) * BK + kq * 8);
    for (int i = 0; i < 4; i++)
      for (int j = 0; j < 2; j++)
        acc[i][j] = __builtin_amdgcn_mfma_f32_16x16x32_f16(a[i], b[j], acc[i][j], 0, 0, 0);
  }

  // C/D layout: col = lane&15 (N), row = (lane>>4)*4 + reg (M)
  int orow0 = by * 128 + wr + (lane >> 4) * 4;
  int ocol0 = bx * 64 + wc + (lane & 15);
  for (int i = 0; i < 4; i++) {
    for (int j = 0; j < 2; j++) {
      int c = ocol0 + j * 16;
      for (int v = 0; v < 4; v++) {
        int r = orow0 + i * 16 + v;
        float val = acc[i][j][v];
        if (c < 1000)       mu[r * 1000 + c] = val;
        else if (c < 2000)  sigma_out[r * 1000 + (c - 1000)] = __expf(0.5f * val);
      }
    }
  }
}

// ---------------- threefry2x32, key = (0, 42) ----------------
// rotl forced to single v_alignbit_b32 (rotl(x,r) == rotr(x,32-r)).
__device__ __forceinline__ unsigned rotl_(unsigned x, unsigned r) {
  return __builtin_amdgcn_alignbit(x, x, 32u - r);
}

__device__ __forceinline__ void threefry(unsigned x0, unsigned x1,
                                         unsigned& o0, unsigned& o1) {
  const unsigned ks1 = 42u;
  const unsigned ks2 = 0x1BD11BDAu ^ 42u;
#define TF_RND(r) { x0 += x1; x1 = rotl_(x1, r); x1 ^= x0; }
  x1 += ks1;
  TF_RND(13) TF_RND(15) TF_RND(26) TF_RND(6)
  x0 += ks1;  x1 += ks2 + 1u;
  TF_RND(17) TF_RND(29) TF_RND(16) TF_RND(24)
  x0 += ks2;  x1 += 2u;
  TF_RND(13) TF_RND(15) TF_RND(26) TF_RND(6)
  x1 += ks1 + 3u;
  TF_RND(17) TF_RND(29) TF_RND(16) TF_RND(24)
  x0 += ks1;  x1 += ks2 + 4u;
  TF_RND(13) TF_RND(15) TF_RND(26) TF_RND(6)
  x0 += ks2;  x1 += 5u;
#undef TF_RND
  o0 = x0; o1 = x1;
}

__device__ __forceinline__ f32x2 splat2(float c) { return (f32x2){c, c}; }

// Tail branch of erfinv; returns p*x WITHOUT the sqrt2 factor
// (sqrt2*log2e is folded into the precomputed sigma scale).
__device__ __forceinline__ float erfinv_big_p(float x, float lg) {
  float w = lg * -0.69314718f;
  float v = __fsqrt_rn(w) - 3.0f;
  float p = -0.000200214257f;
  p = fmaf(p, v, 0.000100950558f);
  p = fmaf(p, v, 0.00134934322f);
  p = fmaf(p, v, -0.00367342844f);
  p = fmaf(p, v, 0.00573950773f);
  p = fmaf(p, v, -0.0076224613f);
  p = fmaf(p, v, 0.00943887047f);
  p = fmaf(p, v, 1.00167406f);
  p = fmaf(p, v, 2.83297682f);
  return p * x;
}

// normal WITHOUT the sqrt2 factor: returns p(v)*x;  v = fma(log2(1-x^2), -ln2, -2.5)
__device__ __forceinline__ f32x2 normal2p(f32x2 x) {
  f32x2 t = __builtin_elementwise_fma(-x, x, splat2(1.0f));
  f32x2 lg;
  lg.x = __builtin_amdgcn_logf(t.x);
  lg.y = __builtin_amdgcn_logf(t.y);
  f32x2 v = __builtin_elementwise_fma(lg, splat2(-0.69314718f), splat2(-2.5f));
  f32x2 p = splat2(2.81022636e-08f);
  p = __builtin_elementwise_fma(p, v, splat2(3.43273939e-07f));
  p = __builtin_elementwise_fma(p, v, splat2(-3.5233877e-06f));
  p = __builtin_elementwise_fma(p, v, splat2(-4.39150654e-06f));
  p = __builtin_elementwise_fma(p, v, splat2(0.00021858087f));
  p = __builtin_elementwise_fma(p, v, splat2(-0.00125372503f));
  p = __builtin_elementwise_fma(p, v, splat2(-0.00417768164f));
  p = __builtin_elementwise_fma(p, v, splat2(0.246640727f));
  p = __builtin_elementwise_fma(p, v, splat2(1.50140941f));
  f32x2 r = p * x;
  if (lg.x <= -7.2134752f) r.x = erfinv_big_p(x.x, lg.x);   // w >= 5, rare
  if (lg.y <= -7.2134752f) r.y = erfinv_big_p(x.y, lg.y);
  return r;
}

__device__ __forceinline__ f32x2 bits_to_u2(unsigned b0, unsigned b1) {
  f32x2 f;
  f.x = __builtin_bit_cast(float, (b0 >> 9) | 0x3f800000u);
  f.y = __builtin_bit_cast(float, (b1 >> 9) | 0x3f800000u);
  f = f - splat2(1.0f);
  return __builtin_elementwise_fma(f, splat2(2.0f), splat2(-0.99999994f));
}

// ---------------- sampling: round-0 structure + exp2 folds + e[] pinned in VGPRs --------
// 1 block per row n; wave w owns t-pairs 4w..4w+3; all 1000 c in 16 reg chunks.
// r10 post-mortem: at VGPR_Count=52 only mu2/sg2/prob were register-resident; the
// compiler RECOMPUTED the threefry->erfinv->exp chain for the prob update (measured
// VALU work 1.85x the one-pass static count). asm volatile pins each e value: inline
// asm results are never rematerializable, so the chain is computed exactly once.
// __launch_bounds__(256,2) caps VGPR at 256 so the ~100-float live set fits unspilled.
__global__ __launch_bounds__(256, 2) void sample_kernel(
    const float* __restrict__ mu,      // ws
    const float* __restrict__ sigma,   // d_out + NC
    float* __restrict__ out0) {        // d_out
  int n    = blockIdx.x;
  int tid  = threadIdx.x;
  int lane = tid & 63, w = tid >> 6;
  __shared__ float pbuf[4][1024];

  // exp(mu + sigma*sqrt2*erfinvp) == exp2( mu*L2E + (sigma*sqrt2*L2E)*erfinvp )
  const float L2E    = 1.44269504f;
  const float SQ2L2E = 1.41421356f * 1.44269504f;

  int cb = n * 1000;
  float mu2[16], sg2[16], prob[16];
#pragma unroll
  for (int j = 0; j < 16; j++) {
    int c = j * 64 + lane;
    bool val = (c < 1000);
    mu2[j]  = val ? mu[cb + c] * L2E       : -1e30f;  // exp2(-1e30)==0: pad classes
    sg2[j]  = val ? sigma[cb + c] * SQ2L2E : 0.f;
    prob[j] = 0.f;
  }

  f32x2 e[16];
#pragma unroll 1
  for (int it = 0; it < 4; it++) {
    int t = w * 4 + it;
    unsigned ib = (unsigned)(t * 4096000 + cb) + (unsigned)lane;
    f32x2 s = splat2(0.f);
#pragma unroll
    for (int j = 0; j < 16; j++) {
      unsigned i0 = ib + (unsigned)(j * 64);
      unsigned o0, o1;
      threefry(i0, i0 + H_HALF, o0, o1);
      f32x2 epsp = normal2p(bits_to_u2(o0, o1));
      float ex = __builtin_amdgcn_exp2f(fmaf(sg2[j], epsp.x, mu2[j]));  // sample t
      float ey = __builtin_amdgcn_exp2f(fmaf(sg2[j], epsp.y, mu2[j]));  // sample t+16
      asm volatile("" : "+v"(ex), "+v"(ey));   // pin: forbid recompute of the chain
      e[j] = (f32x2){ex, ey};
      s.x += ex;
      s.y += ey;
    }
#pragma unroll
    for (int m = 1; m < 64; m <<= 1) {
      s.x += __shfl_xor(s.x, m, 64);
      s.y += __shfl_xor(s.y, m, 64);
    }
    float rA = __builtin_amdgcn_rcpf(s.x);
    float rB = __builtin_amdgcn_rcpf(s.y);
#pragma unroll
    for (int j = 0; j < 16; j++)
      prob[j] = fmaf(e[j].x, rA, fmaf(e[j].y, rB, prob[j]));
  }

#pragma unroll
  for (int j = 0; j < 16; j++)
    pbuf[w][j * 64 + lane] = prob[j];
  __syncthreads();
#pragma unroll
  for (int k = 0; k < 4; k++) {
    int c = tid + k * 256;
    if (c < 1000) {
      float sm = pbuf[0][c] + pbuf[1][c] + pbuf[2][c] + pbuf[3][c];
      out0[cb + c] = __builtin_amdgcn_exp2f(sm * (0.03125f * 1.44269504f));
    }
  }
}

// ---------------- launch ----------------
extern "C" void kernel_launch(void* const* d_in, const int* in_sizes, int n_in,
                              void* d_out, int out_size, void* d_ws, size_t ws_size,
                              hipStream_t stream) {
  const float* x = (const float*)d_in[0];   // 4096*1024
  const float* W = (const float*)d_in[1];   // 2000*1024
  float* out = (float*)d_out;               // [mu_out | sigma], each 4096000

  unsigned short* xh = (unsigned short*)d_ws;                        //  8,388,608 B
  unsigned short* wh = (unsigned short*)((char*)d_ws + 8388608);     //  4,194,304 B
  float*          mu = (float*)((char*)d_ws + 12582912);             // 16,384,000 B
  float* sigma = out + NC_TOT;

  convert_kernel<<<6144, 256, 0, stream>>>(x, W, xh, wh);
  gemm_kernel<<<1024, 256, 0, stream>>>(xh, wh, mu, sigma);
  sample_kernel<<<4096, 256, 0, stream>>>(mu, sigma, out);
}

// Round 6
// 280.501 us; speedup vs baseline: 1.1522x; 1.0008x over previous
//
#include <hip/hip_runtime.h>

// Problem: N=4096, D=1024, C=1000, T=32
//   h = x @ W^T  (4096 x 2000), mu = h[:, :1000], logvar = h[:, 1000:]
//   sigma = exp(0.5*logvar)
//   eps = jax.random.normal(key(42), (32,4096,1000))  -- threefry2x32, bit-exact
//   prob = mean_t softmax(mu + sigma*eps), out0 = exp(prob), out1 = sigma

typedef __attribute__((ext_vector_type(8))) _Float16 f16x8;
typedef __attribute__((ext_vector_type(4))) float f32x4;
typedef __attribute__((ext_vector_type(2))) float f32x2;

#define NC_TOT  4096000
#define H_HALF  65536000u   // half of T*N*C = 131072000

// ---------------- fp32 -> fp16 (RNE) ----------------
__device__ __forceinline__ unsigned short f2h(float f) {
  _Float16 h = (_Float16)f;
  return __builtin_bit_cast(unsigned short, h);
}

__global__ __launch_bounds__(256) void convert_kernel(
    const float* __restrict__ x, const float* __restrict__ W,
    unsigned short* __restrict__ xh, unsigned short* __restrict__ wh) {
  int qid = blockIdx.x * 256 + threadIdx.x;
  if (qid < 1048576) {                        // x: 4096*1024/4
    float4 v = ((const float4*)x)[qid];
    ((ushort4*)xh)[qid] = make_ushort4(f2h(v.x), f2h(v.y), f2h(v.z), f2h(v.w));
  } else {
    int q = qid - 1048576;                    // padded W quad index, < 524288
    int row = q >> 8;
    ushort4 o;
    if (row < 2000) {
      float4 v = ((const float4*)W)[q];
      o = make_ushort4(f2h(v.x), f2h(v.y), f2h(v.z), f2h(v.w));
    } else {
      o = make_ushort4(0, 0, 0, 0);
    }
    ((ushort4*)wh)[q] = o;
  }
}

// ---------------- fp16 MFMA GEMM: 128x64 tiles, 1024 blocks (4/CU) ----------------
// r3 verbatim known-good. Sync-structure edits only in isolated rounds (m152 lesson).
#define BK 32

typedef __attribute__((address_space(3))) unsigned char lds_byte;
typedef __attribute__((address_space(1))) unsigned char glb_byte;

__device__ __forceinline__ void glds16(const unsigned short* g, unsigned short* l) {
  __builtin_amdgcn_global_load_lds((const glb_byte*)g, (lds_byte*)l, 16, 0, 0);
}

__global__ __launch_bounds__(256) void gemm_kernel(
    const unsigned short* __restrict__ Ah,    // [4096][1024] fp16 bits
    const unsigned short* __restrict__ Bh,    // [2048][1024] fp16 bits, padded
    float* __restrict__ mu,                   // [4096][1000]
    float* __restrict__ sigma_out) {          // d_out + NC_TOT
  const int K = 1024;
  __shared__ unsigned short As[128 * BK];     // 8 KB
  __shared__ unsigned short Bs[64 * BK];      // 4 KB

  int id  = blockIdx.x;                 // 0..1023
  int xcd = id & 7;
  int q9  = id >> 3;                    // 0..127
  int by  = xcd * 4 + (q9 >> 5);        // 0..31
  int bx  = q9 & 31;                    // 0..31

  int tid  = threadIdx.x;
  int w    = tid >> 6;
  int lane = tid & 63;
  int wr   = (w >> 1) * 64;             // wave row offset (0/64)
  int wc   = (w & 1) * 32;              // wave col offset (0/32)
  int lrow = lane & 15;
  int kq   = lane >> 4;

  f32x4 acc[4][2];
  for (int i = 0; i < 4; i++)
    for (int j = 0; j < 2; j++) acc[i][j] = (f32x4){0.f, 0.f, 0.f, 0.f};

  int srow = w * 16 + (lane >> 2);
  int scol = (lane & 3) * 8;
  const unsigned short* Ap = Ah + (by * 128 + srow) * K + scol;
  const unsigned short* Bp = Bh + (bx * 64  + srow) * K + scol;   // srow < 64
  unsigned short* lA = As + w * 512;
  unsigned short* lB = Bs + w * 512;

  for (int kk = 0; kk < K; kk += BK) {
    __syncthreads();
    glds16(Ap + kk,          lA);             // A rows 0..63
    glds16(Ap + kk + 64 * K, lA + 2048);      // A rows 64..127
    glds16(Bp + kk,          lB);             // B rows 0..63
    __syncthreads();

    f16x8 a[4], b[2];
    for (int i = 0; i < 4; i++)
      a[i] = *(const f16x8*)(As + (wr + i * 16 + lrow) * BK + kq * 8);
    for (int j = 0; j < 2; j++)
      b[j] = *(const f16x8*)(Bs + (wc + j * 16 + lrow) * BK + kq * 8);
    for (int i = 0; i < 4; i++)
      for (int j = 0; j < 2; j++)
        acc[i][j] = __builtin_amdgcn_mfma_f32_16x16x32_f16(a[i], b[j], acc[i][j], 0, 0, 0);
  }

  // C/D layout: col = lane&15 (N), row = (lane>>4)*4 + reg (M)
  int orow0 = by * 128 + wr + (lane >> 4) * 4;
  int ocol0 = bx * 64 + wc + (lane & 15);
  for (int i = 0; i < 4; i++) {
    for (int j = 0; j < 2; j++) {
      int c = ocol0 + j * 16;
      for (int v = 0; v < 4; v++) {
        int r = orow0 + i * 16 + v;
        float val = acc[i][j][v];
        if (c < 1000)       mu[r * 1000 + c] = val;
        else if (c < 2000)  sigma_out[r * 1000 + (c - 1000)] = __expf(0.5f * val);
      }
    }
  }
}

// ---------------- threefry2x32, key = (0, 42) ----------------
// rotl forced to single v_alignbit_b32 (rotl(x,r) == rotr(x,32-r)).
__device__ __forceinline__ unsigned rotl_(unsigned x, unsigned r) {
  return __builtin_amdgcn_alignbit(x, x, 32u - r);
}

__device__ __forceinline__ void threefry(unsigned x0, unsigned x1,
                                         unsigned& o0, unsigned& o1) {
  const unsigned ks1 = 42u;
  const unsigned ks2 = 0x1BD11BDAu ^ 42u;
#define TF_RND(r) { x0 += x1; x1 = rotl_(x1, r); x1 ^= x0; }
  x1 += ks1;
  TF_RND(13) TF_RND(15) TF_RND(26) TF_RND(6)
  x0 += ks1;  x1 += ks2 + 1u;
  TF_RND(17) TF_RND(29) TF_RND(16) TF_RND(24)
  x0 += ks2;  x1 += 2u;
  TF_RND(13) TF_RND(15) TF_RND(26) TF_RND(6)
  x1 += ks1 + 3u;
  TF_RND(17) TF_RND(29) TF_RND(16) TF_RND(24)
  x0 += ks1;  x1 += ks2 + 4u;
  TF_RND(13) TF_RND(15) TF_RND(26) TF_RND(6)
  x0 += ks2;  x1 += 5u;
#undef TF_RND
  o0 = x0; o1 = x1;
}

__device__ __forceinline__ f32x2 splat2(float c) { return (f32x2){c, c}; }

// Tail branch of erfinv; returns p*x WITHOUT the sqrt2 factor
// (sqrt2*log2e is folded into the precomputed sigma scale).
__device__ __forceinline__ float erfinv_big_p(float x, float lg) {
  float w = lg * -0.69314718f;
  float v = __fsqrt_rn(w) - 3.0f;
  float p = -0.000200214257f;
  p = fmaf(p, v, 0.000100950558f);
  p = fmaf(p, v, 0.00134934322f);
  p = fmaf(p, v, -0.00367342844f);
  p = fmaf(p, v, 0.00573950773f);
  p = fmaf(p, v, -0.0076224613f);
  p = fmaf(p, v, 0.00943887047f);
  p = fmaf(p, v, 1.00167406f);
  p = fmaf(p, v, 2.83297682f);
  return p * x;
}

// normal WITHOUT the sqrt2 factor: returns p(v)*x;  v = fma(log2(1-x^2), -ln2, -2.5)
// r14: r2/r3 passing version, SINGLE change: the two tail fixups are now guarded by a
// wave-uniform __ballot skip instead of being if-converted (always-computed). Tail
// values unchanged when taken -> output bit-identical to r3. If this NaNs, the ballot
// skip is the convicted suspect; if it passes, the r12 pk inline-asm was the bug.
__device__ __forceinline__ f32x2 normal2p(f32x2 x) {
  f32x2 t = __builtin_elementwise_fma(-x, x, splat2(1.0f));
  f32x2 lg;
  lg.x = __builtin_amdgcn_logf(t.x);
  lg.y = __builtin_amdgcn_logf(t.y);
  f32x2 v = __builtin_elementwise_fma(lg, splat2(-0.69314718f), splat2(-2.5f));
  f32x2 p = splat2(2.81022636e-08f);
  p = __builtin_elementwise_fma(p, v, splat2(3.43273939e-07f));
  p = __builtin_elementwise_fma(p, v, splat2(-3.5233877e-06f));
  p = __builtin_elementwise_fma(p, v, splat2(-4.39150654e-06f));
  p = __builtin_elementwise_fma(p, v, splat2(0.00021858087f));
  p = __builtin_elementwise_fma(p, v, splat2(-0.00125372503f));
  p = __builtin_elementwise_fma(p, v, splat2(-0.00417768164f));
  p = __builtin_elementwise_fma(p, v, splat2(0.246640727f));
  p = __builtin_elementwise_fma(p, v, splat2(1.50140941f));
  f32x2 r = p * x;
  bool c0 = lg.x <= -7.2134752f;                 // == (w >= 5), rare (~0.34%/sample)
  bool c1 = lg.y <= -7.2134752f;
  if (__builtin_expect(__ballot(c0 || c1) != 0ull, false)) {
    if (c0) r.x = erfinv_big_p(x.x, lg.x);
    if (c1) r.y = erfinv_big_p(x.y, lg.y);
  }
  return r;
}

__device__ __forceinline__ f32x2 bits_to_u2(unsigned b0, unsigned b1) {
  f32x2 f;
  f.x = __builtin_bit_cast(float, (b0 >> 9) | 0x3f800000u);
  f.y = __builtin_bit_cast(float, (b1 >> 9) | 0x3f800000u);
  f = f - splat2(1.0f);
  return __builtin_elementwise_fma(f, splat2(2.0f), splat2(-0.99999994f));
}

// ---------------- sampling: r3 structure (passing) + ballot-skipped erfinv tail ------
// 1 block per row n; wave w owns t-pairs 4w..4w+3; all 1000 c in 16 reg chunks.
__global__ __launch_bounds__(256, 2) void sample_kernel(
    const float* __restrict__ mu,      // ws
    const float* __restrict__ sigma,   // d_out + NC
    float* __restrict__ out0) {        // d_out
  int n    = blockIdx.x;
  int tid  = threadIdx.x;
  int lane = tid & 63, w = tid >> 6;
  __shared__ float pbuf[4][1024];

  // exp(mu + sigma*sqrt2*erfinvp) == exp2( mu*L2E + (sigma*sqrt2*L2E)*erfinvp )
  const float L2E    = 1.44269504f;
  const float SQ2L2E = 1.41421356f * 1.44269504f;

  int cb = n * 1000;
  float mu2[16], sg2[16], prob[16];
#pragma unroll
  for (int j = 0; j < 16; j++) {
    int c = j * 64 + lane;
    bool val = (c < 1000);
    mu2[j]  = val ? mu[cb + c] * L2E       : -1e30f;  // exp2(-1e30)==0: pad classes
    sg2[j]  = val ? sigma[cb + c] * SQ2L2E : 0.f;
    prob[j] = 0.f;
  }

  f32x2 e[16];
#pragma unroll 1
  for (int it = 0; it < 4; it++) {
    int t = w * 4 + it;
    unsigned ib = (unsigned)(t * 4096000 + cb) + (unsigned)lane;
    f32x2 s = splat2(0.f);
#pragma unroll
    for (int j = 0; j < 16; j++) {
      unsigned i0 = ib + (unsigned)(j * 64);
      unsigned o0, o1;
      threefry(i0, i0 + H_HALF, o0, o1);
      f32x2 epsp = normal2p(bits_to_u2(o0, o1));
      float ex = __builtin_amdgcn_exp2f(fmaf(sg2[j], epsp.x, mu2[j]));  // sample t
      float ey = __builtin_amdgcn_exp2f(fmaf(sg2[j], epsp.y, mu2[j]));  // sample t+16
      asm volatile("" : "+v"(ex), "+v"(ey));   // pin: forbid recompute of the chain
      e[j] = (f32x2){ex, ey};
      s.x += ex;
      s.y += ey;
    }
#pragma unroll
    for (int m = 1; m < 64; m <<= 1) {
      s.x += __shfl_xor(s.x, m, 64);
      s.y += __shfl_xor(s.y, m, 64);
    }
    float rA = __builtin_amdgcn_rcpf(s.x);
    float rB = __builtin_amdgcn_rcpf(s.y);
#pragma unroll
    for (int j = 0; j < 16; j++)
      prob[j] = fmaf(e[j].x, rA, fmaf(e[j].y, rB, prob[j]));
  }

#pragma unroll
  for (int j = 0; j < 16; j++)
    pbuf[w][j * 64 + lane] = prob[j];
  __syncthreads();
#pragma unroll
  for (int k = 0; k < 4; k++) {
    int c = tid + k * 256;
    if (c < 1000) {
      float sm = pbuf[0][c] + pbuf[1][c] + pbuf[2][c] + pbuf[3][c];
      out0[cb + c] = __builtin_amdgcn_exp2f(sm * (0.03125f * 1.44269504f));
    }
  }
}

// ---------------- launch ----------------
extern "C" void kernel_launch(void* const* d_in, const int* in_sizes, int n_in,
                              void* d_out, int out_size, void* d_ws, size_t ws_size,
                              hipStream_t stream) {
  const float* x = (const float*)d_in[0];   // 4096*1024
  const float* W = (const float*)d_in[1];   // 2000*1024
  float* out = (float*)d_out;               // [mu_out | sigma], each 4096000

  unsigned short* xh = (unsigned short*)d_ws;                        //  8,388,608 B
  unsigned short* wh = (unsigned short*)((char*)d_ws + 8388608);     //  4,194,304 B
  float*          mu = (float*)((char*)d_ws + 12582912);             // 16,384,000 B
  float* sigma = out + NC_TOT;

  convert_kernel<<<6144, 256, 0, stream>>>(x, W, xh, wh);
  gemm_kernel<<<1024, 256, 0, stream>>>(xh, wh, mu, sigma);
  sample_kernel<<<4096, 256, 0, stream>>>(mu, sigma, out);
}